// Round 4
// baseline (621.116 us; speedup 1.0000x reference)
//
#include <hip/hip_runtime.h>
#include <hip/hip_bf16.h>

// Problem constants
#define KCODES 2048
#define DIM 256
#define TLEN 2048
#define NB 16
#define NROWS (NB * TLEN)          // 32768 rows (b*t)
#define NELEM (NB * DIM * TLEN)    // 8388608 elements of x / quant
#define LOSS_OFF NELEM             // out[NELEM]=codebook_loss, out[NELEM+1]=commitment_loss
#define IDX_OFF (NELEM + 2)        // out[NELEM+2 ..] = idx (32768) as float

// ws layout (bytes)
#define WS_XSQ   1024                      // 32768 floats
#define WS_ESQ   (WS_XSQ + 131072)         // 2048 floats
#define WS_KEYS  (WS_ESQ + 8192)           // 32768 u64
#define WS_BSUM  (WS_KEYS + 262144)        // 32768 floats

__device__ __forceinline__ float sq_rn(float v) { return __fmul_rn(v, v); }

// ---- keys init (kernel, not memset: keep the capture path kernels-only)
__global__ __launch_bounds__(256) void init_keys_kernel(unsigned long long* __restrict__ keys) {
    keys[blockIdx.x * 256 + threadIdx.x] = ~0ULL;
}

// ---- x_sq: numpy pairwise sum over the 256 contiguous (in xf) elements.
// n=256 -> two halves of 128; each: 8 accumulators strided 8, combined
// ((r0+r1)+(r2+r3))+((r4+r5)+(r6+r7)); halves added.
__global__ __launch_bounds__(256) void xsq_kernel(const float* __restrict__ x,
                                                  float* __restrict__ xsq) {
    int m = blockIdx.x * 256 + threadIdx.x;   // row = b*TLEN + t
    int b = m >> 11, t = m & (TLEN - 1);
    const float* p = x + (size_t)b * DIM * TLEN + t;   // stride TLEN along c
    float h[2];
#pragma unroll
    for (int half = 0; half < 2; ++half) {
        int c0 = half * 128;
        float r[8];
#pragma unroll
        for (int j = 0; j < 8; ++j) r[j] = sq_rn(p[(size_t)(c0 + j) * TLEN]);
        for (int i = 8; i < 128; i += 8) {
#pragma unroll
            for (int j = 0; j < 8; ++j)
                r[j] = __fadd_rn(r[j], sq_rn(p[(size_t)(c0 + i + j) * TLEN]));
        }
        h[half] = __fadd_rn(__fadd_rn(__fadd_rn(r[0], r[1]), __fadd_rn(r[2], r[3])),
                            __fadd_rn(__fadd_rn(r[4], r[5]), __fadd_rn(r[6], r[7])));
    }
    xsq[m] = __fadd_rn(h[0], h[1]);
}

// ---- e_sq over contiguous codebook rows, same numpy pairwise order.
__global__ __launch_bounds__(256) void esq_kernel(const float* __restrict__ cb,
                                                  float* __restrict__ esq) {
    int k = blockIdx.x * 256 + threadIdx.x;
    const float* p = cb + (size_t)k * DIM;
    float h[2];
#pragma unroll
    for (int half = 0; half < 2; ++half) {
        int c0 = half * 128;
        float r[8];
#pragma unroll
        for (int j = 0; j < 8; ++j) r[j] = sq_rn(p[c0 + j]);
        for (int i = 8; i < 128; i += 8) {
#pragma unroll
            for (int j = 0; j < 8; ++j)
                r[j] = __fadd_rn(r[j], sq_rn(p[c0 + i + j]));
        }
        h[half] = __fadd_rn(__fadd_rn(__fadd_rn(r[0], r[1]), __fadd_rn(r[2], r[3])),
                            __fadd_rn(__fadd_rn(r[4], r[5]), __fadd_rn(r[6], r[7])));
    }
    esq[k] = __fadd_rn(h[0], h[1]);
}

// ---- fused distance GEMM + argmin.
// Sequential ascending-k fp32 FMA chain per output element — matches BLAS sgemm
// microkernel accumulation (SIMD across M/N, single chain over K<=kc).
// d2 = fl(fl(x_sq - 2*dot) + e_sq); argmin via packed u64 atomicMin
// (d2 bits << 32 | n) -> first-occurrence (lowest idx) tie-break, np semantics.
__global__ __launch_bounds__(256) void dist_kernel(const float* __restrict__ x,
                                                   const float* __restrict__ cb,
                                                   const float* __restrict__ xsq,
                                                   const float* __restrict__ esq,
                                                   unsigned long long* __restrict__ keys) {
    __shared__ float As[16][64];   // [k][m]
    __shared__ float Bs[16][68];   // [k][n], padded 64->68 (rows stay 16B-aligned: 272B)

    int blk = blockIdx.x;
    int nt = blk & 31, mt = blk >> 5;
    int m0 = mt << 6;
    int b  = m0 >> 11, t0 = m0 & (TLEN - 1);
    int n0 = nt << 6;
    int tid = threadIdx.x;
    int tm = tid >> 4, tn = tid & 15;

    const float* xbase = x + (size_t)b * DIM * TLEN + t0;
    int a_k = tid >> 6, a_m = tid & 63;   // A staging: 4 k-rows per pass
    int b_n = tid >> 4, b_c = tid & 15;   // B staging: 16 n-rows per pass

    float acc[4][4] = {};

    for (int kk = 0; kk < DIM; kk += 16) {
#pragma unroll
        for (int i = 0; i < 4; ++i) {
            int k = a_k + i * 4;
            As[k][a_m] = xbase[(size_t)(kk + k) * TLEN + a_m];
        }
#pragma unroll
        for (int i = 0; i < 4; ++i) {
            int n = b_n + i * 16;
            Bs[b_c][n] = cb[(size_t)(n0 + n) * DIM + kk + b_c];
        }
        __syncthreads();
#pragma unroll
        for (int k = 0; k < 16; ++k) {
            float4 av = *reinterpret_cast<const float4*>(&As[k][tm << 2]);
            float4 bv = *reinterpret_cast<const float4*>(&Bs[k][tn << 2]);
            float am[4] = {av.x, av.y, av.z, av.w};
            float bn[4] = {bv.x, bv.y, bv.z, bv.w};
#pragma unroll
            for (int mi = 0; mi < 4; ++mi)
#pragma unroll
                for (int ni = 0; ni < 4; ++ni)
                    acc[mi][ni] = fmaf(am[mi], bn[ni], acc[mi][ni]);
        }
        __syncthreads();
    }

#pragma unroll
    for (int mi = 0; mi < 4; ++mi) {
        int m = m0 + (tm << 2) + mi;
        float xs = xsq[m];
        float bd = 3.4e38f;
        int   bi = 0x7fffffff;
#pragma unroll
        for (int ni = 0; ni < 4; ++ni) {
            int n = n0 + (tn << 2) + ni;
            // exact reference rounding: fl(fl(xs - 2*dot) + e_sq); 2*dot exact
            float d2 = __fadd_rn(__fadd_rn(xs, -2.0f * acc[mi][ni]), esq[n]);
            if (d2 < bd) { bd = d2; bi = n; }   // strict < keeps first occurrence
        }
        for (int off = 1; off < 16; off <<= 1) {
            float od = __shfl_xor(bd, off, 16);
            int   oi = __shfl_xor(bi, off, 16);
            if (od < bd || (od == bd && oi < bi)) { bd = od; bi = oi; }
        }
        if (tn == 0) {
            unsigned long long key =
                ((unsigned long long)__float_as_uint(bd) << 32) | (unsigned)(bi & 2047);
            atomicMin(&keys[m], key);
        }
    }
}

// ---- gather + straight-through output + idx output + per-block loss sums (fp32 out)
__global__ __launch_bounds__(256) void gather_kernel(const float* __restrict__ x,
                                                     const float* __restrict__ cb,
                                                     const unsigned long long* __restrict__ keys,
                                                     float* __restrict__ out,
                                                     float* __restrict__ bsum) {
    int e = blockIdx.x * 256 + threadIdx.x;
    int t = e & (TLEN - 1);
    int c = (e >> 11) & (DIM - 1);
    int b = e >> 19;
    int m = (b << 11) | t;
    unsigned idx = (unsigned)(keys[m]) & 2047u;   // clamp: no value path may fault
    float q  = cb[(size_t)idx * DIM + c];
    float xv = x[e];
    float diff = __fsub_rn(q, xv);           // quant - x (one rounding, as numpy)
    float o    = __fadd_rn(xv, diff);        // x + (quant - x), numpy STE value
    out[e] = o;
    if (c == 0) out[(size_t)IDX_OFF + m] = (float)idx;

    float s = __fmul_rn(diff, diff);
    for (int off = 32; off > 0; off >>= 1) s += __shfl_down(s, off, 64);
    __shared__ float wsum[4];
    int lane = threadIdx.x & 63, wid = threadIdx.x >> 6;
    if (lane == 0) wsum[wid] = s;
    __syncthreads();
    if (threadIdx.x == 0)
        bsum[blockIdx.x] = ((wsum[0] + wsum[1]) + (wsum[2] + wsum[3]));
}

__global__ __launch_bounds__(256) void finalize_kernel(const float* __restrict__ bsum,
                                                       float* __restrict__ out) {
    double s = 0.0;
    for (int i = threadIdx.x; i < 32768; i += 256) s += (double)bsum[i];
    for (int off = 32; off > 0; off >>= 1) s += __shfl_down(s, off, 64);
    __shared__ double wsum[4];
    int lane = threadIdx.x & 63, wid = threadIdx.x >> 6;
    if (lane == 0) wsum[wid] = s;
    __syncthreads();
    if (threadIdx.x == 0) {
        double total = ((wsum[0] + wsum[1]) + (wsum[2] + wsum[3]));
        float mean = (float)(total / (double)NELEM);
        out[LOSS_OFF]     = mean;                      // codebook_loss
        out[LOSS_OFF + 1] = 0.25f * mean;              // commitment_loss
    }
}

extern "C" void kernel_launch(void* const* d_in, const int* in_sizes, int n_in,
                              void* d_out, int out_size, void* d_ws, size_t ws_size,
                              hipStream_t stream) {
    const float* x  = (const float*)d_in[0];
    const float* cb = (const float*)d_in[1];
    float* out = (float*)d_out;
    char* ws = (char*)d_ws;
    float* xsq = (float*)(ws + WS_XSQ);
    float* esq = (float*)(ws + WS_ESQ);
    unsigned long long* keys = (unsigned long long*)(ws + WS_KEYS);
    float* bsum = (float*)(ws + WS_BSUM);

    init_keys_kernel<<<NROWS / 256, 256, 0, stream>>>(keys);
    xsq_kernel<<<NROWS / 256, 256, 0, stream>>>(x, xsq);
    esq_kernel<<<KCODES / 256, 256, 0, stream>>>(cb, esq);
    dist_kernel<<<(NROWS / 64) * (KCODES / 64), 256, 0, stream>>>(x, cb, xsq, esq, keys);
    gather_kernel<<<NELEM / 256, 256, 0, stream>>>(x, cb, keys, out, bsum);
    finalize_kernel<<<1, 256, 0, stream>>>(bsum, out);
}

// Round 5
// 566.927 us; speedup vs baseline: 1.0956x; 1.0956x over previous
//
#include <hip/hip_runtime.h>
#include <hip/hip_bf16.h>

// Problem constants
#define KCODES 2048
#define DIM 256
#define TLEN 2048
#define NB 16
#define NROWS (NB * TLEN)          // 32768 rows (b*t)
#define NELEM (NB * DIM * TLEN)    // 8388608 elements of x / quant
#define LOSS_OFF NELEM             // out[NELEM]=codebook_loss, out[NELEM+1]=commitment_loss
#define IDX_OFF (NELEM + 2)        // out[NELEM+2 ..] = idx (32768) as float

// ws layout (bytes)
#define WS_XSQ   1024                      // 32768 floats
#define WS_ESQ   (WS_XSQ + 131072)         // 2048 floats
#define WS_KEYS  (WS_ESQ + 8192)           // 32768 u64
#define WS_BSUM  (WS_KEYS + 262144)        // 32768 floats

__device__ __forceinline__ float sq_rn(float v) { return __fmul_rn(v, v); }

// ---- keys init (kernel, not memset: capture path stays kernels-only)
__global__ __launch_bounds__(256) void init_keys_kernel(unsigned long long* __restrict__ keys) {
    keys[blockIdx.x * 256 + threadIdx.x] = ~0ULL;
}

// ---- x_sq: numpy pairwise sum over the 256 contiguous (in xf) elements.
__global__ __launch_bounds__(256) void xsq_kernel(const float* __restrict__ x,
                                                  float* __restrict__ xsq) {
    int m = blockIdx.x * 256 + threadIdx.x;   // row = b*TLEN + t
    int b = m >> 11, t = m & (TLEN - 1);
    const float* p = x + (size_t)b * DIM * TLEN + t;   // stride TLEN along c
    float h[2];
#pragma unroll
    for (int half = 0; half < 2; ++half) {
        int c0 = half * 128;
        float r[8];
#pragma unroll
        for (int j = 0; j < 8; ++j) r[j] = sq_rn(p[(size_t)(c0 + j) * TLEN]);
        for (int i = 8; i < 128; i += 8) {
#pragma unroll
            for (int j = 0; j < 8; ++j)
                r[j] = __fadd_rn(r[j], sq_rn(p[(size_t)(c0 + i + j) * TLEN]));
        }
        h[half] = __fadd_rn(__fadd_rn(__fadd_rn(r[0], r[1]), __fadd_rn(r[2], r[3])),
                            __fadd_rn(__fadd_rn(r[4], r[5]), __fadd_rn(r[6], r[7])));
    }
    xsq[m] = __fadd_rn(h[0], h[1]);
}

// ---- e_sq over contiguous codebook rows, same numpy pairwise order.
__global__ __launch_bounds__(256) void esq_kernel(const float* __restrict__ cb,
                                                  float* __restrict__ esq) {
    int k = blockIdx.x * 256 + threadIdx.x;
    const float* p = cb + (size_t)k * DIM;
    float h[2];
#pragma unroll
    for (int half = 0; half < 2; ++half) {
        int c0 = half * 128;
        float r[8];
#pragma unroll
        for (int j = 0; j < 8; ++j) r[j] = sq_rn(p[c0 + j]);
        for (int i = 8; i < 128; i += 8) {
#pragma unroll
            for (int j = 0; j < 8; ++j)
                r[j] = __fadd_rn(r[j], sq_rn(p[c0 + i + j]));
        }
        h[half] = __fadd_rn(__fadd_rn(__fadd_rn(r[0], r[1]), __fadd_rn(r[2], r[3])),
                            __fadd_rn(__fadd_rn(r[4], r[5]), __fadd_rn(r[6], r[7])));
    }
    esq[k] = __fadd_rn(h[0], h[1]);
}

// ---- fused distance GEMM + argmin. 128x128 tile, 8x8 micro-tile.
// Split fragments {4t, 64+4t}: each b128-quad spans 256B contiguous LDS ->
// <=2-way bank aliasing (free). Per (m,n): identical ascending-k fmaf chain
// as Round 4 (bit-exact vs np). LDS bytes/FMA halved: 4 b128 per 64 FMA.
__global__ __launch_bounds__(256, 4) void dist_kernel(const float* __restrict__ x,
                                                      const float* __restrict__ cb,
                                                      const float* __restrict__ xsq,
                                                      const float* __restrict__ esq,
                                                      unsigned long long* __restrict__ keys) {
    __shared__ float As[16][128];   // [k][m]  8 KB
    __shared__ float Bs[16][132];   // [k][n]  pad 128->132: staging-write conflicts ~2-way,
                                    // rows stay 16B-aligned (528 B)

    int blk = blockIdx.x;
    int nt = blk & 15, mt = blk >> 4;           // n fast: A-tile L2 reuse
    int m0 = mt << 7;
    int b  = m0 >> 11, t0 = m0 & (TLEN - 1);    // 128 | 2048 -> single b per tile
    int n0 = nt << 7;
    int tid = threadIdx.x;
    int tm = tid >> 4, tn = tid & 15;

    const float* xbase = x + (size_t)b * DIM * TLEN + t0;

    float acc[8][8] = {};

    for (int kk = 0; kk < DIM; kk += 16) {
        // A staging: 2048 floats as 512 float4; q -> k=q>>5, m=(q&31)*4
#pragma unroll
        for (int h = 0; h < 2; ++h) {
            int q = tid + (h << 8);
            int k = q >> 5, mq = (q & 31) << 2;
            float4 v = *reinterpret_cast<const float4*>(xbase + (size_t)(kk + k) * TLEN + mq);
            *reinterpret_cast<float4*>(&As[k][mq]) = v;
        }
        // B staging (transpose-on-store): q -> nr=q>>2, kc=q&3
#pragma unroll
        for (int h = 0; h < 2; ++h) {
            int q = tid + (h << 8);
            int nr = q >> 2, kc = (q & 3) << 2;
            float4 v = *reinterpret_cast<const float4*>(cb + (size_t)(n0 + nr) * DIM + kk + kc);
            Bs[kc + 0][nr] = v.x; Bs[kc + 1][nr] = v.y;
            Bs[kc + 2][nr] = v.z; Bs[kc + 3][nr] = v.w;
        }
        __syncthreads();
#pragma unroll
        for (int k = 0; k < 16; ++k) {
            float4 a0 = *reinterpret_cast<const float4*>(&As[k][tm << 2]);
            float4 a1 = *reinterpret_cast<const float4*>(&As[k][64 + (tm << 2)]);
            float4 b0 = *reinterpret_cast<const float4*>(&Bs[k][tn << 2]);
            float4 b1 = *reinterpret_cast<const float4*>(&Bs[k][64 + (tn << 2)]);
            float am[8] = {a0.x, a0.y, a0.z, a0.w, a1.x, a1.y, a1.z, a1.w};
            float bn[8] = {b0.x, b0.y, b0.z, b0.w, b1.x, b1.y, b1.z, b1.w};
#pragma unroll
            for (int mi = 0; mi < 8; ++mi)
#pragma unroll
                for (int ni = 0; ni < 8; ++ni)
                    acc[mi][ni] = fmaf(am[mi], bn[ni], acc[mi][ni]);
        }
        __syncthreads();
    }

    // epilogue: cols cn[ni] ascending (4tn..4tn+3, 64+4tn..64+4tn+3)
    int cn[8]; float es[8];
#pragma unroll
    for (int ni = 0; ni < 8; ++ni) {
        cn[ni] = n0 + ((ni < 4) ? (tn << 2) + ni : 60 + (tn << 2) + ni);
        es[ni] = esq[cn[ni]];
    }
#pragma unroll
    for (int mi = 0; mi < 8; ++mi) {
        int m = m0 + ((mi < 4) ? (tm << 2) + mi : 60 + (tm << 2) + mi);
        float xs = xsq[m];
        float bd = 3.4e38f;
        int   bi = 0x7fffffff;
#pragma unroll
        for (int ni = 0; ni < 8; ++ni) {
            // exact reference rounding: fl(fl(xs - 2*dot) + e_sq); 2*dot exact
            float d2 = __fadd_rn(__fadd_rn(xs, -2.0f * acc[mi][ni]), es[ni]);
            if (d2 < bd) { bd = d2; bi = cn[ni]; }   // ascending order: first-occurrence ties
        }
        for (int off = 1; off < 16; off <<= 1) {
            float od = __shfl_xor(bd, off, 16);
            int   oi = __shfl_xor(bi, off, 16);
            if (od < bd || (od == bd && oi < bi)) { bd = od; bi = oi; }
        }
        if (tn == 0) {
            unsigned long long key =
                ((unsigned long long)__float_as_uint(bd) << 32) | (unsigned)(bi & 2047);
            atomicMin(&keys[m], key);
        }
    }
}

// ---- gather + straight-through output + idx output + per-block loss sums (fp32 out)
__global__ __launch_bounds__(256) void gather_kernel(const float* __restrict__ x,
                                                     const float* __restrict__ cb,
                                                     const unsigned long long* __restrict__ keys,
                                                     float* __restrict__ out,
                                                     float* __restrict__ bsum) {
    int e = blockIdx.x * 256 + threadIdx.x;
    int t = e & (TLEN - 1);
    int c = (e >> 11) & (DIM - 1);
    int b = e >> 19;
    int m = (b << 11) | t;
    unsigned idx = (unsigned)(keys[m]) & 2047u;   // clamp: no value path may fault
    float q  = cb[(size_t)idx * DIM + c];
    float xv = x[e];
    float diff = __fsub_rn(q, xv);           // quant - x (one rounding, as numpy)
    float o    = __fadd_rn(xv, diff);        // x + (quant - x), numpy STE value
    out[e] = o;
    if (c == 0) out[(size_t)IDX_OFF + m] = (float)idx;

    float s = __fmul_rn(diff, diff);
    for (int off = 32; off > 0; off >>= 1) s += __shfl_down(s, off, 64);
    __shared__ float wsum[4];
    int lane = threadIdx.x & 63, wid = threadIdx.x >> 6;
    if (lane == 0) wsum[wid] = s;
    __syncthreads();
    if (threadIdx.x == 0)
        bsum[blockIdx.x] = ((wsum[0] + wsum[1]) + (wsum[2] + wsum[3]));
}

__global__ __launch_bounds__(1024) void finalize_kernel(const float* __restrict__ bsum,
                                                        float* __restrict__ out) {
    double s = 0.0;
    for (int i = threadIdx.x; i < 32768; i += 1024) s += (double)bsum[i];
    for (int off = 32; off > 0; off >>= 1) s += __shfl_down(s, off, 64);
    __shared__ double wsum[16];
    int lane = threadIdx.x & 63, wid = threadIdx.x >> 6;
    if (lane == 0) wsum[wid] = s;
    __syncthreads();
    if (threadIdx.x == 0) {
        double total = 0.0;
        for (int w = 0; w < 16; ++w) total += wsum[w];
        float mean = (float)(total / (double)NELEM);
        out[LOSS_OFF]     = mean;                      // codebook_loss
        out[LOSS_OFF + 1] = 0.25f * mean;              // commitment_loss
    }
}

extern "C" void kernel_launch(void* const* d_in, const int* in_sizes, int n_in,
                              void* d_out, int out_size, void* d_ws, size_t ws_size,
                              hipStream_t stream) {
    const float* x  = (const float*)d_in[0];
    const float* cb = (const float*)d_in[1];
    float* out = (float*)d_out;
    char* ws = (char*)d_ws;
    float* xsq = (float*)(ws + WS_XSQ);
    float* esq = (float*)(ws + WS_ESQ);
    unsigned long long* keys = (unsigned long long*)(ws + WS_KEYS);
    float* bsum = (float*)(ws + WS_BSUM);

    init_keys_kernel<<<NROWS / 256, 256, 0, stream>>>(keys);
    xsq_kernel<<<NROWS / 256, 256, 0, stream>>>(x, xsq);
    esq_kernel<<<KCODES / 256, 256, 0, stream>>>(cb, esq);
    dist_kernel<<<(NROWS / 128) * (KCODES / 128), 256, 0, stream>>>(x, cb, xsq, esq, keys);
    gather_kernel<<<NELEM / 256, 256, 0, stream>>>(x, cb, keys, out, bsum);
    finalize_kernel<<<1, 1024, 0, stream>>>(bsum, out);
}

// Round 6
// 455.217 us; speedup vs baseline: 1.3644x; 1.2454x over previous
//
#include <hip/hip_runtime.h>
#include <hip/hip_bf16.h>

// Problem constants
#define KCODES 2048
#define DIM 256
#define TLEN 2048
#define NB 16
#define NROWS (NB * TLEN)          // 32768 rows (b*t)
#define NELEM (NB * DIM * TLEN)    // 8388608 elements of x / quant
#define LOSS_OFF NELEM
#define IDX_OFF (NELEM + 2)

#define MARGIN 4e-4f

// ws layout (bytes)
#define OFF_XSQ   0ull                       // 131072
#define OFF_ESQ   131072ull                  // 8192
#define OFF_KEYS  139264ull                  // 262144
#define OFF_BSUM  401408ull                  // 131072
#define OFF_XHI   532480ull                  // 16777216
#define OFF_XLO   17309696ull                // 16777216
#define OFF_EHI   34086912ull                // 1048576
#define OFF_ELO   35135488ull                // 1048576
#define OFF_LMIN  36184064ull                // 8388608
#define OFF_MASK  44572672ull                // 8388608
#define WS_NEED   52961280ull

typedef __bf16 bf16x8 __attribute__((ext_vector_type(8)));
typedef float  f32x4  __attribute__((ext_vector_type(4)));

__device__ __forceinline__ float sq_rn(float v) { return __fmul_rn(v, v); }

// ---- x_sq: numpy pairwise sum (8-acc/128-block) — bit-exact vs np
__global__ __launch_bounds__(256) void xsq_kernel(const float* __restrict__ x,
                                                  float* __restrict__ xsq) {
    int m = blockIdx.x * 256 + threadIdx.x;
    int b = m >> 11, t = m & (TLEN - 1);
    const float* p = x + (size_t)b * DIM * TLEN + t;
    float h[2];
#pragma unroll
    for (int half = 0; half < 2; ++half) {
        int c0 = half * 128;
        float r[8];
#pragma unroll
        for (int j = 0; j < 8; ++j) r[j] = sq_rn(p[(size_t)(c0 + j) * TLEN]);
        for (int i = 8; i < 128; i += 8) {
#pragma unroll
            for (int j = 0; j < 8; ++j)
                r[j] = __fadd_rn(r[j], sq_rn(p[(size_t)(c0 + i + j) * TLEN]));
        }
        h[half] = __fadd_rn(__fadd_rn(__fadd_rn(r[0], r[1]), __fadd_rn(r[2], r[3])),
                            __fadd_rn(__fadd_rn(r[4], r[5]), __fadd_rn(r[6], r[7])));
    }
    xsq[m] = __fadd_rn(h[0], h[1]);
}

__global__ __launch_bounds__(256) void esq_kernel(const float* __restrict__ cb,
                                                  float* __restrict__ esq) {
    int k = blockIdx.x * 256 + threadIdx.x;
    const float* p = cb + (size_t)k * DIM;
    float h[2];
#pragma unroll
    for (int half = 0; half < 2; ++half) {
        int c0 = half * 128;
        float r[8];
#pragma unroll
        for (int j = 0; j < 8; ++j) r[j] = sq_rn(p[c0 + j]);
        for (int i = 8; i < 128; i += 8) {
#pragma unroll
            for (int j = 0; j < 8; ++j)
                r[j] = __fadd_rn(r[j], sq_rn(p[c0 + i + j]));
        }
        h[half] = __fadd_rn(__fadd_rn(__fadd_rn(r[0], r[1]), __fadd_rn(r[2], r[3])),
                            __fadd_rn(__fadd_rn(r[4], r[5]), __fadd_rn(r[6], r[7])));
    }
    esq[k] = __fadd_rn(h[0], h[1]);
}

// ---- split x (layout [c][t] fp32) -> Xhi/Xlo [m][k] bf16 (transpose + Dekker split)
__global__ __launch_bounds__(256) void split_x_kernel(const float* __restrict__ x,
                                                      __hip_bfloat16* __restrict__ Xhi,
                                                      __hip_bfloat16* __restrict__ Xlo) {
    __shared__ float tb[32][72];
    int blk = blockIdx.x;
    int tt = blk & 31, cc = (blk >> 5) & 7, b = blk >> 8;
    int c0 = cc << 5, t0 = tt << 6;
    int tid = threadIdx.x;
    {   // load 32c x 64t coalesced
        int c_l = tid >> 3, t8 = (tid & 7) << 3;
        const float* src = x + (size_t)b * DIM * TLEN + (size_t)(c0 + c_l) * TLEN + t0 + t8;
        float4 v0 = *reinterpret_cast<const float4*>(src);
        float4 v1 = *reinterpret_cast<const float4*>(src + 4);
        tb[c_l][t8 + 0] = v0.x; tb[c_l][t8 + 1] = v0.y; tb[c_l][t8 + 2] = v0.z; tb[c_l][t8 + 3] = v0.w;
        tb[c_l][t8 + 4] = v1.x; tb[c_l][t8 + 5] = v1.y; tb[c_l][t8 + 6] = v1.z; tb[c_l][t8 + 7] = v1.w;
    }
    __syncthreads();
    {   // write: thread -> (m_l, 8-c segment)
        int cp = tid & 3, m_l = tid >> 2;
        size_t m = (size_t)b * TLEN + t0 + m_l;
        alignas(16) __hip_bfloat16 h8[8];
        alignas(16) __hip_bfloat16 l8[8];
#pragma unroll
        for (int j = 0; j < 8; ++j) {
            float f = tb[(cp << 3) + j][m_l];
            __hip_bfloat16 hi = __float2bfloat16(f);
            __hip_bfloat16 lo = __float2bfloat16(__fsub_rn(f, __bfloat162float(hi)));
            h8[j] = hi; l8[j] = lo;
        }
        *reinterpret_cast<int4*>(Xhi + m * DIM + c0 + (cp << 3)) = *reinterpret_cast<int4*>(h8);
        *reinterpret_cast<int4*>(Xlo + m * DIM + c0 + (cp << 3)) = *reinterpret_cast<int4*>(l8);
    }
}

// ---- split codebook [n][k] fp32 -> Ehi/Elo [n][k] bf16
__global__ __launch_bounds__(256) void split_e_kernel(const float* __restrict__ cb,
                                                      __hip_bfloat16* __restrict__ Ehi,
                                                      __hip_bfloat16* __restrict__ Elo) {
    int i4 = (blockIdx.x * 256 + threadIdx.x) << 2;
    float4 v = *reinterpret_cast<const float4*>(cb + i4);
    alignas(8) __hip_bfloat16 h4[4];
    alignas(8) __hip_bfloat16 l4[4];
    float f[4] = {v.x, v.y, v.z, v.w};
#pragma unroll
    for (int j = 0; j < 4; ++j) {
        __hip_bfloat16 hi = __float2bfloat16(f[j]);
        h4[j] = hi;
        l4[j] = __float2bfloat16(__fsub_rn(f[j], __bfloat162float(hi)));
    }
    *reinterpret_cast<int2*>(Ehi + i4) = *reinterpret_cast<int2*>(h4);
    *reinterpret_cast<int2*>(Elo + i4) = *reinterpret_cast<int2*>(l4);
}

// ---- Phase A: MFMA approx distance + per-(row, 64-col-tile) local min & margin mask.
// dot ~= xhi*ehi + xhi*elo + xlo*ehi (3 bf16 MFMA sweeps, fp32 acc).
// 128x128 tile, 4 waves each 64x64 via 4x4 grid of 16x16x32 MFMAs.
__global__ __launch_bounds__(256) void mfma_dist_kernel(const __hip_bfloat16* __restrict__ Xhi,
                                                        const __hip_bfloat16* __restrict__ Xlo,
                                                        const __hip_bfloat16* __restrict__ Ehi,
                                                        const __hip_bfloat16* __restrict__ Elo,
                                                        const float* __restrict__ xsq,
                                                        const float* __restrict__ esq,
                                                        unsigned long long* __restrict__ lmin,
                                                        unsigned long long* __restrict__ lmask) {
    // k-stride 40 elems (80 B): frag b128 reads conflict-free (8-lane phases hit disjoint 4-bank windows)
    __shared__ __hip_bfloat16 Ah[128 * 40], Al[128 * 40], Bh[128 * 40], Bl[128 * 40];
    int blk = blockIdx.x;
    int nt = blk & 15, mt = blk >> 4;
    int m0 = mt << 7, n0 = nt << 7;
    int tid = threadIdx.x;
    int w = tid >> 6, lane = tid & 63;
    int q = lane >> 4, c = lane & 15;
    int mhalf = w >> 1, nhalf = w & 1;

    f32x4 acc[4][4];
#pragma unroll
    for (int mi = 0; mi < 4; ++mi)
#pragma unroll
        for (int ni = 0; ni < 4; ++ni) acc[mi][ni] = (f32x4){0.f, 0.f, 0.f, 0.f};

    for (int kk = 0; kk < DIM; kk += 32) {
#pragma unroll
        for (int h = 0; h < 2; ++h) {
            int qq = tid + (h << 8);
            int mm = qq >> 2, s4 = (qq & 3) << 3;            // 8-bf16 (16B) segment
            size_t ga = (size_t)(m0 + mm) * DIM + kk + s4;
            size_t gb = (size_t)(n0 + mm) * DIM + kk + s4;
            int lo_off = mm * 40 + s4;
            *reinterpret_cast<int4*>(&Ah[lo_off]) = *reinterpret_cast<const int4*>(Xhi + ga);
            *reinterpret_cast<int4*>(&Al[lo_off]) = *reinterpret_cast<const int4*>(Xlo + ga);
            *reinterpret_cast<int4*>(&Bh[lo_off]) = *reinterpret_cast<const int4*>(Ehi + gb);
            *reinterpret_cast<int4*>(&Bl[lo_off]) = *reinterpret_cast<const int4*>(Elo + gb);
        }
        __syncthreads();
        bf16x8 ah[4], al[4], bh[4], bl[4];
#pragma unroll
        for (int mi = 0; mi < 4; ++mi) {
            int ro = (mhalf * 64 + mi * 16 + c) * 40 + q * 8;
            ah[mi] = *reinterpret_cast<const bf16x8*>(&Ah[ro]);
            al[mi] = *reinterpret_cast<const bf16x8*>(&Al[ro]);
        }
#pragma unroll
        for (int ni = 0; ni < 4; ++ni) {
            int ro = (nhalf * 64 + ni * 16 + c) * 40 + q * 8;
            bh[ni] = *reinterpret_cast<const bf16x8*>(&Bh[ro]);
            bl[ni] = *reinterpret_cast<const bf16x8*>(&Bl[ro]);
        }
#pragma unroll
        for (int mi = 0; mi < 4; ++mi)
#pragma unroll
            for (int ni = 0; ni < 4; ++ni) {
                acc[mi][ni] = __builtin_amdgcn_mfma_f32_16x16x32_bf16(ah[mi], bh[ni], acc[mi][ni], 0, 0, 0);
                acc[mi][ni] = __builtin_amdgcn_mfma_f32_16x16x32_bf16(ah[mi], bl[ni], acc[mi][ni], 0, 0, 0);
                acc[mi][ni] = __builtin_amdgcn_mfma_f32_16x16x32_bf16(al[mi], bh[ni], acc[mi][ni], 0, 0, 0);
            }
        __syncthreads();
    }

    // epilogue: per row, local min over this wave's 64 cols + margin mask
    int tb = (nt << 1) | nhalf;      // 64-col tile index 0..31
#pragma unroll
    for (int mi = 0; mi < 4; ++mi) {
#pragma unroll
        for (int reg = 0; reg < 4; ++reg) {
            int m = m0 + mhalf * 64 + mi * 16 + q * 4 + reg;
            float xs = xsq[m];
            float bd = 3.4e38f; int bi = 0;
            float dv[4];
#pragma unroll
            for (int ni = 0; ni < 4; ++ni) {
                int n = n0 + nhalf * 64 + ni * 16 + c;
                float d2 = xs - 2.0f * acc[mi][ni][reg] + esq[n];
                dv[ni] = d2;
                if (d2 < bd) { bd = d2; bi = ni * 16 + c; }
            }
            for (int off = 1; off < 16; off <<= 1) {
                float od = __shfl_xor(bd, off, 16);
                int   oi = __shfl_xor(bi, off, 16);
                if (od < bd || (od == bd && oi < bi)) { bd = od; bi = oi; }
            }
            float thr = bd + MARGIN;
            unsigned long long bits = 0;
#pragma unroll
            for (int ni = 0; ni < 4; ++ni)
                if (dv[ni] <= thr) bits |= 1ULL << (ni * 16 + c);
            for (int off = 1; off < 16; off <<= 1)
                bits |= (unsigned long long)__shfl_xor((long long)bits, off, 16);
            if (c == 0) {
                lmin[(size_t)m * 32 + tb] =
                    ((unsigned long long)__float_as_uint(bd) << 32) | (unsigned)(n0 + nhalf * 64 + bi);
                lmask[(size_t)m * 32 + tb] = bits;
            }
        }
    }
}

// ---- Phase B: row min over 32 tiles, exact np-chain recheck of masked candidates.
__global__ __launch_bounds__(256) void recheck_kernel(const float* __restrict__ x,
                                                      const float* __restrict__ cb,
                                                      const float* __restrict__ xsq,
                                                      const float* __restrict__ esq,
                                                      const unsigned long long* __restrict__ lmin,
                                                      const unsigned long long* __restrict__ lmask,
                                                      unsigned long long* __restrict__ keys) {
    __shared__ float xrow[4][256];
    __shared__ int clist[4][160];
    int w = threadIdx.x >> 6, lane = threadIdx.x & 63;
    int m = blockIdx.x * 4 + w;
    int b = m >> 11, t = m & (TLEN - 1);
#pragma unroll
    for (int i = 0; i < 4; ++i) {
        int k = lane + (i << 6);
        xrow[w][k] = x[(size_t)b * DIM * TLEN + (size_t)k * TLEN + t];
    }
    int tl = lane & 31;
    unsigned long long lm = lmin[(size_t)m * 32 + tl];
    unsigned rmv = (unsigned)(lm >> 32);
    unsigned rm = rmv;
    for (int off = 1; off < 64; off <<= 1) {
        unsigned o = (unsigned)__shfl_xor((int)rm, off, 64);
        rm = min(rm, o);
    }
    float thr = __uint_as_float(rm) + MARGIN;
    unsigned long long msk = 0;
    if (lane < 32 && __uint_as_float(rmv) <= thr) msk = lmask[(size_t)m * 32 + tl];
    int cnt = __popcll(msk);
    int sum = cnt;
    for (int off = 1; off < 64; off <<= 1) {
        int o = __shfl_up(sum, off, 64);
        if (lane >= off) sum += o;
    }
    int excl = sum - cnt;
    int L = __shfl(sum, 63, 64);
    unsigned long long mm2 = msk; int pos = excl;
    while (mm2) {
        int bpos = __ffsll((long long)mm2) - 1;
        mm2 &= mm2 - 1;
        if (pos < 160) clist[w][pos] = tl * 64 + bpos;
        ++pos;
    }
    if (L > 160) L = 160;
    __syncthreads();
    float bd = 3.4e38f; int bi = 0x7fffffff;
    float xs = xsq[m];
    for (int c0 = 0; c0 < L; c0 += 64) {
        int j = c0 + lane;
        if (j < L) {
            int n = clist[w][j];
            const float* crow = cb + (size_t)n * DIM;
            float d = 0.f;
            for (int k = 0; k < 256; k += 4) {     // ascending-k fmaf chain == np mm
                float4 cv = *reinterpret_cast<const float4*>(crow + k);
                d = fmaf(xrow[w][k + 0], cv.x, d);
                d = fmaf(xrow[w][k + 1], cv.y, d);
                d = fmaf(xrow[w][k + 2], cv.z, d);
                d = fmaf(xrow[w][k + 3], cv.w, d);
            }
            float d2 = __fadd_rn(__fadd_rn(xs, -2.0f * d), esq[n]);   // exact ref rounding
            if (d2 < bd || (d2 == bd && n < bi)) { bd = d2; bi = n; }
        }
    }
    for (int off = 1; off < 64; off <<= 1) {
        float od = __shfl_xor(bd, off, 64);
        int   oi = __shfl_xor(bi, off, 64);
        if (od < bd || (od == bd && oi < bi)) { bd = od; bi = oi; }
    }
    if (lane == 0)
        keys[m] = ((unsigned long long)__float_as_uint(bd) << 32) | (unsigned)(bi & 2047);
}

// ======== fallback path (R5): used only if ws_size is too small ========
__global__ __launch_bounds__(256) void init_keys_kernel(unsigned long long* __restrict__ keys) {
    keys[blockIdx.x * 256 + threadIdx.x] = ~0ULL;
}

__global__ __launch_bounds__(256, 4) void dist_kernel(const float* __restrict__ x,
                                                      const float* __restrict__ cb,
                                                      const float* __restrict__ xsq,
                                                      const float* __restrict__ esq,
                                                      unsigned long long* __restrict__ keys) {
    __shared__ float As[16][128];
    __shared__ float Bs[16][132];
    int blk = blockIdx.x;
    int nt = blk & 15, mt = blk >> 4;
    int m0 = mt << 7;
    int b = m0 >> 11, t0 = m0 & (TLEN - 1);
    int n0 = nt << 7;
    int tid = threadIdx.x;
    int tm = tid >> 4, tn = tid & 15;
    const float* xbase = x + (size_t)b * DIM * TLEN + t0;
    float acc[8][8] = {};
    for (int kk = 0; kk < DIM; kk += 16) {
#pragma unroll
        for (int h = 0; h < 2; ++h) {
            int qq = tid + (h << 8);
            int k = qq >> 5, mq = (qq & 31) << 2;
            float4 v = *reinterpret_cast<const float4*>(xbase + (size_t)(kk + k) * TLEN + mq);
            *reinterpret_cast<float4*>(&As[k][mq]) = v;
        }
#pragma unroll
        for (int h = 0; h < 2; ++h) {
            int qq = tid + (h << 8);
            int nr = qq >> 2, kc = (qq & 3) << 2;
            float4 v = *reinterpret_cast<const float4*>(cb + (size_t)(n0 + nr) * DIM + kk + kc);
            Bs[kc + 0][nr] = v.x; Bs[kc + 1][nr] = v.y;
            Bs[kc + 2][nr] = v.z; Bs[kc + 3][nr] = v.w;
        }
        __syncthreads();
#pragma unroll
        for (int k = 0; k < 16; ++k) {
            float4 a0 = *reinterpret_cast<const float4*>(&As[k][tm << 2]);
            float4 a1 = *reinterpret_cast<const float4*>(&As[k][64 + (tm << 2)]);
            float4 b0 = *reinterpret_cast<const float4*>(&Bs[k][tn << 2]);
            float4 b1 = *reinterpret_cast<const float4*>(&Bs[k][64 + (tn << 2)]);
            float am[8] = {a0.x, a0.y, a0.z, a0.w, a1.x, a1.y, a1.z, a1.w};
            float bn[8] = {b0.x, b0.y, b0.z, b0.w, b1.x, b1.y, b1.z, b1.w};
#pragma unroll
            for (int mi = 0; mi < 8; ++mi)
#pragma unroll
                for (int ni = 0; ni < 8; ++ni)
                    acc[mi][ni] = fmaf(am[mi], bn[ni], acc[mi][ni]);
        }
        __syncthreads();
    }
    int cn[8]; float es[8];
#pragma unroll
    for (int ni = 0; ni < 8; ++ni) {
        cn[ni] = n0 + ((ni < 4) ? (tn << 2) + ni : 60 + (tn << 2) + ni);
        es[ni] = esq[cn[ni]];
    }
#pragma unroll
    for (int mi = 0; mi < 8; ++mi) {
        int m = m0 + ((mi < 4) ? (tm << 2) + mi : 60 + (tm << 2) + mi);
        float xs = xsq[m];
        float bd = 3.4e38f;
        int bi = 0x7fffffff;
#pragma unroll
        for (int ni = 0; ni < 8; ++ni) {
            float d2 = __fadd_rn(__fadd_rn(xs, -2.0f * acc[mi][ni]), es[ni]);
            if (d2 < bd) { bd = d2; bi = cn[ni]; }
        }
        for (int off = 1; off < 16; off <<= 1) {
            float od = __shfl_xor(bd, off, 16);
            int oi = __shfl_xor(bi, off, 16);
            if (od < bd || (od == bd && oi < bi)) { bd = od; bi = oi; }
        }
        if (tn == 0) {
            unsigned long long key =
                ((unsigned long long)__float_as_uint(bd) << 32) | (unsigned)(bi & 2047);
            atomicMin(&keys[m], key);
        }
    }
}
// ======== end fallback ========

// ---- gather + STE output + idx + per-block loss sums
__global__ __launch_bounds__(256) void gather_kernel(const float* __restrict__ x,
                                                     const float* __restrict__ cb,
                                                     const unsigned long long* __restrict__ keys,
                                                     float* __restrict__ out,
                                                     float* __restrict__ bsum) {
    int e = blockIdx.x * 256 + threadIdx.x;
    int t = e & (TLEN - 1);
    int c = (e >> 11) & (DIM - 1);
    int b = e >> 19;
    int m = (b << 11) | t;
    unsigned idx = (unsigned)(keys[m]) & 2047u;
    float q = cb[(size_t)idx * DIM + c];
    float xv = x[e];
    float diff = __fsub_rn(q, xv);
    float o = __fadd_rn(xv, diff);
    out[e] = o;
    if (c == 0) out[(size_t)IDX_OFF + m] = (float)idx;

    float s = __fmul_rn(diff, diff);
    for (int off = 32; off > 0; off >>= 1) s += __shfl_down(s, off, 64);
    __shared__ float wsum[4];
    int lane = threadIdx.x & 63, wid = threadIdx.x >> 6;
    if (lane == 0) wsum[wid] = s;
    __syncthreads();
    if (threadIdx.x == 0)
        bsum[blockIdx.x] = ((wsum[0] + wsum[1]) + (wsum[2] + wsum[3]));
}

__global__ __launch_bounds__(1024) void finalize_kernel(const float* __restrict__ bsum,
                                                        float* __restrict__ out) {
    double s = 0.0;
    for (int i = threadIdx.x; i < 32768; i += 1024) s += (double)bsum[i];
    for (int off = 32; off > 0; off >>= 1) s += __shfl_down(s, off, 64);
    __shared__ double wsum[16];
    int lane = threadIdx.x & 63, wid = threadIdx.x >> 6;
    if (lane == 0) wsum[wid] = s;
    __syncthreads();
    if (threadIdx.x == 0) {
        double total = 0.0;
        for (int ww = 0; ww < 16; ++ww) total += wsum[ww];
        float mean = (float)(total / (double)NELEM);
        out[LOSS_OFF] = mean;
        out[LOSS_OFF + 1] = 0.25f * mean;
    }
}

extern "C" void kernel_launch(void* const* d_in, const int* in_sizes, int n_in,
                              void* d_out, int out_size, void* d_ws, size_t ws_size,
                              hipStream_t stream) {
    const float* x  = (const float*)d_in[0];
    const float* cb = (const float*)d_in[1];
    float* out = (float*)d_out;
    char* ws = (char*)d_ws;
    float* xsq = (float*)(ws + OFF_XSQ);
    float* esq = (float*)(ws + OFF_ESQ);
    unsigned long long* keys = (unsigned long long*)(ws + OFF_KEYS);
    float* bsum = (float*)(ws + OFF_BSUM);

    xsq_kernel<<<NROWS / 256, 256, 0, stream>>>(x, xsq);
    esq_kernel<<<KCODES / 256, 256, 0, stream>>>(cb, esq);

    if (ws_size >= WS_NEED) {
        __hip_bfloat16* Xhi = (__hip_bfloat16*)(ws + OFF_XHI);
        __hip_bfloat16* Xlo = (__hip_bfloat16*)(ws + OFF_XLO);
        __hip_bfloat16* Ehi = (__hip_bfloat16*)(ws + OFF_EHI);
        __hip_bfloat16* Elo = (__hip_bfloat16*)(ws + OFF_ELO);
        unsigned long long* lmin  = (unsigned long long*)(ws + OFF_LMIN);
        unsigned long long* lmask = (unsigned long long*)(ws + OFF_MASK);
        split_x_kernel<<<NB * 8 * 32, 256, 0, stream>>>(x, Xhi, Xlo);
        split_e_kernel<<<(KCODES * DIM) / 1024, 256, 0, stream>>>(cb, Ehi, Elo);
        mfma_dist_kernel<<<(NROWS / 128) * (KCODES / 128), 256, 0, stream>>>(
            Xhi, Xlo, Ehi, Elo, xsq, esq, lmin, lmask);
        recheck_kernel<<<NROWS / 4, 256, 0, stream>>>(x, cb, xsq, esq, lmin, lmask, keys);
    } else {
        init_keys_kernel<<<NROWS / 256, 256, 0, stream>>>(keys);
        dist_kernel<<<(NROWS / 128) * (KCODES / 128), 256, 0, stream>>>(x, cb, xsq, esq, keys);
    }
    gather_kernel<<<NELEM / 256, 256, 0, stream>>>(x, cb, keys, out, bsum);
    finalize_kernel<<<1, 1024, 0, stream>>>(bsum, out);
}

// Round 8
// 356.940 us; speedup vs baseline: 1.7401x; 1.2753x over previous
//
#include <hip/hip_runtime.h>
#include <hip/hip_bf16.h>

// Problem constants
#define KCODES 2048
#define DIM 256
#define TLEN 2048
#define NB 16
#define NROWS (NB * TLEN)          // 32768 rows (b*t)
#define NELEM (NB * DIM * TLEN)    // 8388608 elements of x / quant
#define LOSS_OFF NELEM
#define IDX_OFF (NELEM + 2)

// Approx filter margin. Single hi*hi bf16 sweep: dropped cross-terms give
// d2 error rms ~2.8e-5 (bf16 rel err 2^-8); containment needs 2*err+eval
// rounding <= MARGIN. 3e-3 requires a ~50-sigma event to miss. Candidates
// within 3e-3 of row min: ~2-6 per row (recheck list holds 256).
#define MARGIN 3e-3f

// ws layout (bytes) — total 35.1 MB
#define OFF_XSQ   0ull                       // 131072
#define OFF_ESQ   131072ull                  // 8192
#define OFF_KEYS  139264ull                  // 262144
#define OFF_BSUM  401408ull                  // 131072
#define OFF_XHI   532480ull                  // 16777216
#define OFF_EHI   17309696ull                // 1048576
#define OFF_LMIN  18358272ull                // 8388608
#define OFF_MASK  26746880ull                // 8388608
#define WS_NEED   35135488ull

typedef __bf16 bf16x8 __attribute__((ext_vector_type(8)));
typedef float  f32x4  __attribute__((ext_vector_type(4)));

__device__ __forceinline__ float sq_rn(float v) { return __fmul_rn(v, v); }

// ---- x_sq: numpy pairwise sum (8-acc/128-block) — bit-exact vs np
__global__ __launch_bounds__(256) void xsq_kernel(const float* __restrict__ x,
                                                  float* __restrict__ xsq) {
    int m = blockIdx.x * 256 + threadIdx.x;
    int b = m >> 11, t = m & (TLEN - 1);
    const float* p = x + (size_t)b * DIM * TLEN + t;
    float h[2];
#pragma unroll
    for (int half = 0; half < 2; ++half) {
        int c0 = half * 128;
        float r[8];
#pragma unroll
        for (int j = 0; j < 8; ++j) r[j] = sq_rn(p[(size_t)(c0 + j) * TLEN]);
        for (int i = 8; i < 128; i += 8) {
#pragma unroll
            for (int j = 0; j < 8; ++j)
                r[j] = __fadd_rn(r[j], sq_rn(p[(size_t)(c0 + i + j) * TLEN]));
        }
        h[half] = __fadd_rn(__fadd_rn(__fadd_rn(r[0], r[1]), __fadd_rn(r[2], r[3])),
                            __fadd_rn(__fadd_rn(r[4], r[5]), __fadd_rn(r[6], r[7])));
    }
    xsq[m] = __fadd_rn(h[0], h[1]);
}

__global__ __launch_bounds__(256) void esq_kernel(const float* __restrict__ cb,
                                                  float* __restrict__ esq) {
    int k = blockIdx.x * 256 + threadIdx.x;
    const float* p = cb + (size_t)k * DIM;
    float h[2];
#pragma unroll
    for (int half = 0; half < 2; ++half) {
        int c0 = half * 128;
        float r[8];
#pragma unroll
        for (int j = 0; j < 8; ++j) r[j] = sq_rn(p[c0 + j]);
        for (int i = 8; i < 128; i += 8) {
#pragma unroll
            for (int j = 0; j < 8; ++j)
                r[j] = __fadd_rn(r[j], sq_rn(p[c0 + i + j]));
        }
        h[half] = __fadd_rn(__fadd_rn(__fadd_rn(r[0], r[1]), __fadd_rn(r[2], r[3])),
                            __fadd_rn(__fadd_rn(r[4], r[5]), __fadd_rn(r[6], r[7])));
    }
    esq[k] = __fadd_rn(h[0], h[1]);
}

// ---- x (layout [c][t] fp32) -> Xhi [m][k] bf16 (transpose + round)
__global__ __launch_bounds__(256) void split_x_kernel(const float* __restrict__ x,
                                                      __hip_bfloat16* __restrict__ Xhi) {
    __shared__ float tb[32][72];
    int blk = blockIdx.x;
    int tt = blk & 31, cc = (blk >> 5) & 7, b = blk >> 8;
    int c0 = cc << 5, t0 = tt << 6;
    int tid = threadIdx.x;
    {
        int c_l = tid >> 3, t8 = (tid & 7) << 3;
        const float* src = x + (size_t)b * DIM * TLEN + (size_t)(c0 + c_l) * TLEN + t0 + t8;
        float4 v0 = *reinterpret_cast<const float4*>(src);
        float4 v1 = *reinterpret_cast<const float4*>(src + 4);
        tb[c_l][t8 + 0] = v0.x; tb[c_l][t8 + 1] = v0.y; tb[c_l][t8 + 2] = v0.z; tb[c_l][t8 + 3] = v0.w;
        tb[c_l][t8 + 4] = v1.x; tb[c_l][t8 + 5] = v1.y; tb[c_l][t8 + 6] = v1.z; tb[c_l][t8 + 7] = v1.w;
    }
    __syncthreads();
    {
        int cp = tid & 3, m_l = tid >> 2;
        size_t m = (size_t)b * TLEN + t0 + m_l;
        alignas(16) __hip_bfloat16 h8[8];
#pragma unroll
        for (int j = 0; j < 8; ++j)
            h8[j] = __float2bfloat16(tb[(cp << 3) + j][m_l]);
        *reinterpret_cast<int4*>(Xhi + m * DIM + c0 + (cp << 3)) = *reinterpret_cast<int4*>(h8);
    }
}

// ---- codebook [n][k] fp32 -> Ehi [n][k] bf16
__global__ __launch_bounds__(256) void split_e_kernel(const float* __restrict__ cb,
                                                      __hip_bfloat16* __restrict__ Ehi) {
    int i4 = (blockIdx.x * 256 + threadIdx.x) << 2;
    float4 v = *reinterpret_cast<const float4*>(cb + i4);
    alignas(8) __hip_bfloat16 h4[4];
    h4[0] = __float2bfloat16(v.x); h4[1] = __float2bfloat16(v.y);
    h4[2] = __float2bfloat16(v.z); h4[3] = __float2bfloat16(v.w);
    *reinterpret_cast<int2*>(Ehi + i4) = *reinterpret_cast<int2*>(h4);
}

// ---- Phase A: single-sweep bf16 MFMA approx distance + per-(row, 64-col-tile)
// local min & margin mask. 128x128 tile, BK=32, R6-PROVEN ds_write staging
// (stride-40 rows) — glds staging from R7 produced wrong LDS contents, reverted.
__global__ __launch_bounds__(256, 4) void mfma_dist_kernel(const __hip_bfloat16* __restrict__ Xhi,
                                                           const __hip_bfloat16* __restrict__ Ehi,
                                                           const float* __restrict__ xsq,
                                                           const float* __restrict__ esq,
                                                           unsigned long long* __restrict__ lmin,
                                                           unsigned long long* __restrict__ lmask) {
    __shared__ __hip_bfloat16 Ah[128 * 40];   // [row][32 k], 80B stride, 10KB
    __shared__ __hip_bfloat16 Bh[128 * 40];   // 10KB

    int blk = blockIdx.x;
    int nt = blk & 15, mt = blk >> 4;
    int m0 = mt << 7, n0 = nt << 7;
    int tid = threadIdx.x;
    int w = tid >> 6, lane = tid & 63;
    int q = lane >> 4, c = lane & 15;
    int mhalf = w >> 1, nhalf = w & 1;

    f32x4 acc[4][4];
#pragma unroll
    for (int mi = 0; mi < 4; ++mi)
#pragma unroll
        for (int ni = 0; ni < 4; ++ni) acc[mi][ni] = (f32x4){0.f, 0.f, 0.f, 0.f};

    for (int kk = 0; kk < DIM; kk += 32) {
#pragma unroll
        for (int h = 0; h < 2; ++h) {
            int qq = tid + (h << 8);
            int mm = qq >> 2, s4 = (qq & 3) << 3;            // 8-bf16 (16B) segment
            size_t ga = (size_t)(m0 + mm) * DIM + kk + s4;
            size_t gb = (size_t)(n0 + mm) * DIM + kk + s4;
            int lo_off = mm * 40 + s4;
            *reinterpret_cast<int4*>(&Ah[lo_off]) = *reinterpret_cast<const int4*>(Xhi + ga);
            *reinterpret_cast<int4*>(&Bh[lo_off]) = *reinterpret_cast<const int4*>(Ehi + gb);
        }
        __syncthreads();
        bf16x8 ah[4], bh[4];
#pragma unroll
        for (int mi = 0; mi < 4; ++mi) {
            int ro = (mhalf * 64 + mi * 16 + c) * 40 + q * 8;
            ah[mi] = *reinterpret_cast<const bf16x8*>(&Ah[ro]);
        }
#pragma unroll
        for (int ni = 0; ni < 4; ++ni) {
            int ro = (nhalf * 64 + ni * 16 + c) * 40 + q * 8;
            bh[ni] = *reinterpret_cast<const bf16x8*>(&Bh[ro]);
        }
#pragma unroll
        for (int mi = 0; mi < 4; ++mi)
#pragma unroll
            for (int ni = 0; ni < 4; ++ni)
                acc[mi][ni] = __builtin_amdgcn_mfma_f32_16x16x32_bf16(ah[mi], bh[ni], acc[mi][ni], 0, 0, 0);
        __syncthreads();
    }

    // epilogue: per row, local min over this wave's 64 cols + margin mask
    int tb = (nt << 1) | nhalf;
#pragma unroll
    for (int mi = 0; mi < 4; ++mi) {
#pragma unroll
        for (int reg = 0; reg < 4; ++reg) {
            int m = m0 + mhalf * 64 + mi * 16 + q * 4 + reg;
            float xs = xsq[m];
            float bd = 3.4e38f; int bi = 0;
            float dv[4];
#pragma unroll
            for (int ni = 0; ni < 4; ++ni) {
                int n = n0 + nhalf * 64 + ni * 16 + c;
                float d2 = xs - 2.0f * acc[mi][ni][reg] + esq[n];
                dv[ni] = d2;
                if (d2 < bd) { bd = d2; bi = ni * 16 + c; }
            }
            for (int off = 1; off < 16; off <<= 1) {
                float od = __shfl_xor(bd, off, 16);
                int   oi = __shfl_xor(bi, off, 16);
                if (od < bd || (od == bd && oi < bi)) { bd = od; bi = oi; }
            }
            float thr = bd + MARGIN;
            unsigned long long bits = 0;
#pragma unroll
            for (int ni = 0; ni < 4; ++ni)
                if (dv[ni] <= thr) bits |= 1ULL << (ni * 16 + c);
            for (int off = 1; off < 16; off <<= 1)
                bits |= (unsigned long long)__shfl_xor((long long)bits, off, 16);
            if (c == 0) {
                lmin[(size_t)m * 32 + tb] =
                    ((unsigned long long)__float_as_uint(bd) << 32) | (unsigned)(n0 + nhalf * 64 + bi);
                lmask[(size_t)m * 32 + tb] = bits;
            }
        }
    }
}

// ---- Phase B: row min over 32 tiles, exact np-chain recheck of candidates.
__global__ __launch_bounds__(256) void recheck_kernel(const float* __restrict__ x,
                                                      const float* __restrict__ cb,
                                                      const float* __restrict__ xsq,
                                                      const float* __restrict__ esq,
                                                      const unsigned long long* __restrict__ lmin,
                                                      const unsigned long long* __restrict__ lmask,
                                                      unsigned long long* __restrict__ keys) {
    __shared__ float xrow[4][256];
    __shared__ int clist[4][256];
    int w = threadIdx.x >> 6, lane = threadIdx.x & 63;
    int m = blockIdx.x * 4 + w;
    int b = m >> 11, t = m & (TLEN - 1);
#pragma unroll
    for (int i = 0; i < 4; ++i) {
        int k = lane + (i << 6);
        xrow[w][k] = x[(size_t)b * DIM * TLEN + (size_t)k * TLEN + t];
    }
    int tl = lane & 31;
    unsigned long long lm = lmin[(size_t)m * 32 + tl];
    unsigned rmv = (unsigned)(lm >> 32);
    unsigned rm = rmv;
    for (int off = 1; off < 64; off <<= 1) {
        unsigned o = (unsigned)__shfl_xor((int)rm, off, 64);
        rm = min(rm, o);
    }
    float thr = __uint_as_float(rm) + MARGIN;
    unsigned long long msk = 0;
    if (lane < 32 && __uint_as_float(rmv) <= thr) msk = lmask[(size_t)m * 32 + tl];
    int cnt = __popcll(msk);
    int sum = cnt;
    for (int off = 1; off < 64; off <<= 1) {
        int o = __shfl_up(sum, off, 64);
        if (lane >= off) sum += o;
    }
    int excl = sum - cnt;
    int L = __shfl(sum, 63, 64);
    unsigned long long mm2 = msk; int pos = excl;
    while (mm2) {
        int bpos = __ffsll((long long)mm2) - 1;
        mm2 &= mm2 - 1;
        if (pos < 256) clist[w][pos] = tl * 64 + bpos;
        ++pos;
    }
    if (L > 256) L = 256;
    __syncthreads();
    float bd = 3.4e38f; int bi = 0x7fffffff;
    float xs = xsq[m];
    for (int c0 = 0; c0 < L; c0 += 64) {
        int j = c0 + lane;
        if (j < L) {
            int n = clist[w][j];
            const float* crow = cb + (size_t)n * DIM;
            float d = 0.f;
            for (int k = 0; k < 256; k += 4) {     // ascending-k fmaf chain == np mm
                float4 cv = *reinterpret_cast<const float4*>(crow + k);
                d = fmaf(xrow[w][k + 0], cv.x, d);
                d = fmaf(xrow[w][k + 1], cv.y, d);
                d = fmaf(xrow[w][k + 2], cv.z, d);
                d = fmaf(xrow[w][k + 3], cv.w, d);
            }
            float d2 = __fadd_rn(__fadd_rn(xs, -2.0f * d), esq[n]);   // exact ref rounding
            if (d2 < bd || (d2 == bd && n < bi)) { bd = d2; bi = n; }
        }
    }
    for (int off = 1; off < 64; off <<= 1) {
        float od = __shfl_xor(bd, off, 64);
        int   oi = __shfl_xor(bi, off, 64);
        if (od < bd || (od == bd && oi < bi)) { bd = od; bi = oi; }
    }
    if (lane == 0)
        keys[m] = ((unsigned long long)__float_as_uint(bd) << 32) | (unsigned)(bi & 2047);
}

// ======== fallback path (R5): used only if ws_size is too small ========
__global__ __launch_bounds__(256) void init_keys_kernel(unsigned long long* __restrict__ keys) {
    keys[blockIdx.x * 256 + threadIdx.x] = ~0ULL;
}

__global__ __launch_bounds__(256, 4) void dist_kernel(const float* __restrict__ x,
                                                      const float* __restrict__ cb,
                                                      const float* __restrict__ xsq,
                                                      const float* __restrict__ esq,
                                                      unsigned long long* __restrict__ keys) {
    __shared__ float As[16][128];
    __shared__ float Bs[16][132];
    int blk = blockIdx.x;
    int nt = blk & 15, mt = blk >> 4;
    int m0 = mt << 7;
    int b = m0 >> 11, t0 = m0 & (TLEN - 1);
    int n0 = nt << 7;
    int tid = threadIdx.x;
    int tm = tid >> 4, tn = tid & 15;
    const float* xbase = x + (size_t)b * DIM * TLEN + t0;
    float acc[8][8] = {};
    for (int kk = 0; kk < DIM; kk += 16) {
#pragma unroll
        for (int h = 0; h < 2; ++h) {
            int qq = tid + (h << 8);
            int k = qq >> 5, mq = (qq & 31) << 2;
            float4 v = *reinterpret_cast<const float4*>(xbase + (size_t)(kk + k) * TLEN + mq);
            *reinterpret_cast<float4*>(&As[k][mq]) = v;
        }
#pragma unroll
        for (int h = 0; h < 2; ++h) {
            int qq = tid + (h << 8);
            int nr = qq >> 2, kc = (qq & 3) << 2;
            float4 v = *reinterpret_cast<const float4*>(cb + (size_t)(n0 + nr) * DIM + kk + kc);
            Bs[kc + 0][nr] = v.x; Bs[kc + 1][nr] = v.y;
            Bs[kc + 2][nr] = v.z; Bs[kc + 3][nr] = v.w;
        }
        __syncthreads();
#pragma unroll
        for (int k = 0; k < 16; ++k) {
            float4 a0 = *reinterpret_cast<const float4*>(&As[k][tm << 2]);
            float4 a1 = *reinterpret_cast<const float4*>(&As[k][64 + (tm << 2)]);
            float4 b0 = *reinterpret_cast<const float4*>(&Bs[k][tn << 2]);
            float4 b1 = *reinterpret_cast<const float4*>(&Bs[k][64 + (tn << 2)]);
            float am[8] = {a0.x, a0.y, a0.z, a0.w, a1.x, a1.y, a1.z, a1.w};
            float bn[8] = {b0.x, b0.y, b0.z, b0.w, b1.x, b1.y, b1.z, b1.w};
#pragma unroll
            for (int mi = 0; mi < 8; ++mi)
#pragma unroll
                for (int ni = 0; ni < 8; ++ni)
                    acc[mi][ni] = fmaf(am[mi], bn[ni], acc[mi][ni]);
        }
        __syncthreads();
    }
    int cn[8]; float es[8];
#pragma unroll
    for (int ni = 0; ni < 8; ++ni) {
        cn[ni] = n0 + ((ni < 4) ? (tn << 2) + ni : 60 + (tn << 2) + ni);
        es[ni] = esq[cn[ni]];
    }
#pragma unroll
    for (int mi = 0; mi < 8; ++mi) {
        int m = m0 + ((mi < 4) ? (tm << 2) + mi : 60 + (tm << 2) + mi);
        float xs = xsq[m];
        float bd = 3.4e38f;
        int bi = 0x7fffffff;
#pragma unroll
        for (int ni = 0; ni < 8; ++ni) {
            float d2 = __fadd_rn(__fadd_rn(xs, -2.0f * acc[mi][ni]), es[ni]);
            if (d2 < bd) { bd = d2; bi = cn[ni]; }
        }
        for (int off = 1; off < 16; off <<= 1) {
            float od = __shfl_xor(bd, off, 16);
            int oi = __shfl_xor(bi, off, 16);
            if (od < bd || (od == bd && oi < bi)) { bd = od; bi = oi; }
        }
        if (tn == 0) {
            unsigned long long key =
                ((unsigned long long)__float_as_uint(bd) << 32) | (unsigned)(bi & 2047);
            atomicMin(&keys[m], key);
        }
    }
}
// ======== end fallback ========

// ---- gather + STE output + idx + per-block loss sums
__global__ __launch_bounds__(256) void gather_kernel(const float* __restrict__ x,
                                                     const float* __restrict__ cb,
                                                     const unsigned long long* __restrict__ keys,
                                                     float* __restrict__ out,
                                                     float* __restrict__ bsum) {
    int e = blockIdx.x * 256 + threadIdx.x;
    int t = e & (TLEN - 1);
    int c = (e >> 11) & (DIM - 1);
    int b = e >> 19;
    int m = (b << 11) | t;
    unsigned idx = (unsigned)(keys[m]) & 2047u;
    float q = cb[(size_t)idx * DIM + c];
    float xv = x[e];
    float diff = __fsub_rn(q, xv);
    float o = __fadd_rn(xv, diff);
    out[e] = o;
    if (c == 0) out[(size_t)IDX_OFF + m] = (float)idx;

    float s = __fmul_rn(diff, diff);
    for (int off = 32; off > 0; off >>= 1) s += __shfl_down(s, off, 64);
    __shared__ float wsum[4];
    int lane = threadIdx.x & 63, wid = threadIdx.x >> 6;
    if (lane == 0) wsum[wid] = s;
    __syncthreads();
    if (threadIdx.x == 0)
        bsum[blockIdx.x] = ((wsum[0] + wsum[1]) + (wsum[2] + wsum[3]));
}

__global__ __launch_bounds__(1024) void finalize_kernel(const float* __restrict__ bsum,
                                                        float* __restrict__ out) {
    double s = 0.0;
    for (int i = threadIdx.x; i < 32768; i += 1024) s += (double)bsum[i];
    for (int off = 32; off > 0; off >>= 1) s += __shfl_down(s, off, 64);
    __shared__ double wsum[16];
    int lane = threadIdx.x & 63, wid = threadIdx.x >> 6;
    if (lane == 0) wsum[wid] = s;
    __syncthreads();
    if (threadIdx.x == 0) {
        double total = 0.0;
        for (int ww = 0; ww < 16; ++ww) total += wsum[ww];
        float mean = (float)(total / (double)NELEM);
        out[LOSS_OFF] = mean;
        out[LOSS_OFF + 1] = 0.25f * mean;
    }
}

extern "C" void kernel_launch(void* const* d_in, const int* in_sizes, int n_in,
                              void* d_out, int out_size, void* d_ws, size_t ws_size,
                              hipStream_t stream) {
    const float* x  = (const float*)d_in[0];
    const float* cb = (const float*)d_in[1];
    float* out = (float*)d_out;
    char* ws = (char*)d_ws;
    float* xsq = (float*)(ws + OFF_XSQ);
    float* esq = (float*)(ws + OFF_ESQ);
    unsigned long long* keys = (unsigned long long*)(ws + OFF_KEYS);
    float* bsum = (float*)(ws + OFF_BSUM);

    xsq_kernel<<<NROWS / 256, 256, 0, stream>>>(x, xsq);
    esq_kernel<<<KCODES / 256, 256, 0, stream>>>(cb, esq);

    if (ws_size >= WS_NEED) {
        __hip_bfloat16* Xhi = (__hip_bfloat16*)(ws + OFF_XHI);
        __hip_bfloat16* Ehi = (__hip_bfloat16*)(ws + OFF_EHI);
        unsigned long long* lmin  = (unsigned long long*)(ws + OFF_LMIN);
        unsigned long long* lmask = (unsigned long long*)(ws + OFF_MASK);
        split_x_kernel<<<NB * 8 * 32, 256, 0, stream>>>(x, Xhi);
        split_e_kernel<<<(KCODES * DIM) / 1024, 256, 0, stream>>>(cb, Ehi);
        mfma_dist_kernel<<<(NROWS / 128) * (KCODES / 128), 256, 0, stream>>>(
            Xhi, Ehi, xsq, esq, lmin, lmask);
        recheck_kernel<<<NROWS / 4, 256, 0, stream>>>(x, cb, xsq, esq, lmin, lmask, keys);
    } else {
        init_keys_kernel<<<NROWS / 256, 256, 0, stream>>>(keys);
        dist_kernel<<<(NROWS / 128) * (KCODES / 128), 256, 0, stream>>>(x, cb, xsq, esq, keys);
    }
    gather_kernel<<<NELEM / 256, 256, 0, stream>>>(x, cb, keys, out, bsum);
    finalize_kernel<<<1, 1024, 0, stream>>>(bsum, out);
}

// Round 9
// 279.712 us; speedup vs baseline: 2.2206x; 1.2761x over previous
//
#include <hip/hip_runtime.h>
#include <hip/hip_bf16.h>

// Problem constants
#define KCODES 2048
#define DIM 256
#define TLEN 2048
#define NB 16
#define NROWS (NB * TLEN)          // 32768 rows (b*t)
#define NELEM (NB * DIM * TLEN)    // 8388608 elements of x / quant
#define LOSS_OFF NELEM
#define IDX_OFF (NELEM + 2)

// Approx filter margin (see R8: ~50-sigma safety for single hi*hi sweep).
#define MARGIN 3e-3f

// ws layout (bytes) — total 35.1 MB
#define OFF_XSQ   0ull                       // 131072
#define OFF_ESQ   131072ull                  // 8192
#define OFF_KEYS  139264ull                  // 262144
#define OFF_BSUM  401408ull                  // 131072
#define OFF_XHI   532480ull                  // 16777216
#define OFF_EHI   17309696ull                // 1048576
#define OFF_LMIN  18358272ull                // 8388608
#define OFF_MASK  26746880ull                // 8388608
#define WS_NEED   35135488ull

typedef __bf16 bf16x8 __attribute__((ext_vector_type(8)));
typedef float  f32x4  __attribute__((ext_vector_type(4)));

__device__ __forceinline__ float sq_rn(float v) { return __fmul_rn(v, v); }

// ---- x_sq: numpy pairwise sum (8-acc/128-block) — bit-exact vs np
__global__ __launch_bounds__(256) void xsq_kernel(const float* __restrict__ x,
                                                  float* __restrict__ xsq) {
    int m = blockIdx.x * 256 + threadIdx.x;
    int b = m >> 11, t = m & (TLEN - 1);
    const float* p = x + (size_t)b * DIM * TLEN + t;
    float h[2];
#pragma unroll
    for (int half = 0; half < 2; ++half) {
        int c0 = half * 128;
        float r[8];
#pragma unroll
        for (int j = 0; j < 8; ++j) r[j] = sq_rn(p[(size_t)(c0 + j) * TLEN]);
        for (int i = 8; i < 128; i += 8) {
#pragma unroll
            for (int j = 0; j < 8; ++j)
                r[j] = __fadd_rn(r[j], sq_rn(p[(size_t)(c0 + i + j) * TLEN]));
        }
        h[half] = __fadd_rn(__fadd_rn(__fadd_rn(r[0], r[1]), __fadd_rn(r[2], r[3])),
                            __fadd_rn(__fadd_rn(r[4], r[5]), __fadd_rn(r[6], r[7])));
    }
    xsq[m] = __fadd_rn(h[0], h[1]);
}

__global__ __launch_bounds__(256) void esq_kernel(const float* __restrict__ cb,
                                                  float* __restrict__ esq) {
    int k = blockIdx.x * 256 + threadIdx.x;
    const float* p = cb + (size_t)k * DIM;
    float h[2];
#pragma unroll
    for (int half = 0; half < 2; ++half) {
        int c0 = half * 128;
        float r[8];
#pragma unroll
        for (int j = 0; j < 8; ++j) r[j] = sq_rn(p[c0 + j]);
        for (int i = 8; i < 128; i += 8) {
#pragma unroll
            for (int j = 0; j < 8; ++j)
                r[j] = __fadd_rn(r[j], sq_rn(p[c0 + i + j]));
        }
        h[half] = __fadd_rn(__fadd_rn(__fadd_rn(r[0], r[1]), __fadd_rn(r[2], r[3])),
                            __fadd_rn(__fadd_rn(r[4], r[5]), __fadd_rn(r[6], r[7])));
    }
    esq[k] = __fadd_rn(h[0], h[1]);
}

// ---- x (layout [c][t] fp32) -> Xhi [m][k] bf16 (transpose + round)
__global__ __launch_bounds__(256) void split_x_kernel(const float* __restrict__ x,
                                                      __hip_bfloat16* __restrict__ Xhi) {
    __shared__ float tb[32][72];
    int blk = blockIdx.x;
    int tt = blk & 31, cc = (blk >> 5) & 7, b = blk >> 8;
    int c0 = cc << 5, t0 = tt << 6;
    int tid = threadIdx.x;
    {
        int c_l = tid >> 3, t8 = (tid & 7) << 3;
        const float* src = x + (size_t)b * DIM * TLEN + (size_t)(c0 + c_l) * TLEN + t0 + t8;
        float4 v0 = *reinterpret_cast<const float4*>(src);
        float4 v1 = *reinterpret_cast<const float4*>(src + 4);
        tb[c_l][t8 + 0] = v0.x; tb[c_l][t8 + 1] = v0.y; tb[c_l][t8 + 2] = v0.z; tb[c_l][t8 + 3] = v0.w;
        tb[c_l][t8 + 4] = v1.x; tb[c_l][t8 + 5] = v1.y; tb[c_l][t8 + 6] = v1.z; tb[c_l][t8 + 7] = v1.w;
    }
    __syncthreads();
    {
        int cp = tid & 3, m_l = tid >> 2;
        size_t m = (size_t)b * TLEN + t0 + m_l;
        alignas(16) __hip_bfloat16 h8[8];
#pragma unroll
        for (int j = 0; j < 8; ++j)
            h8[j] = __float2bfloat16(tb[(cp << 3) + j][m_l]);
        *reinterpret_cast<int4*>(Xhi + m * DIM + c0 + (cp << 3)) = *reinterpret_cast<int4*>(h8);
    }
}

// ---- codebook [n][k] fp32 -> Ehi [n][k] bf16
__global__ __launch_bounds__(256) void split_e_kernel(const float* __restrict__ cb,
                                                      __hip_bfloat16* __restrict__ Ehi) {
    int i4 = (blockIdx.x * 256 + threadIdx.x) << 2;
    float4 v = *reinterpret_cast<const float4*>(cb + i4);
    alignas(8) __hip_bfloat16 h4[4];
    h4[0] = __float2bfloat16(v.x); h4[1] = __float2bfloat16(v.y);
    h4[2] = __float2bfloat16(v.z); h4[3] = __float2bfloat16(v.w);
    *reinterpret_cast<int2*>(Ehi + i4) = *reinterpret_cast<int2*>(h4);
}

// ---- Phase A: single-sweep bf16 MFMA approx distance + per-(row, 64-col-tile)
// local min & margin mask. 128x128 tile, BK=32, R6-proven ds_write staging.
__global__ __launch_bounds__(256, 4) void mfma_dist_kernel(const __hip_bfloat16* __restrict__ Xhi,
                                                           const __hip_bfloat16* __restrict__ Ehi,
                                                           const float* __restrict__ xsq,
                                                           const float* __restrict__ esq,
                                                           unsigned long long* __restrict__ lmin,
                                                           unsigned long long* __restrict__ lmask) {
    __shared__ __hip_bfloat16 Ah[128 * 40];   // [row][32 k], 80B stride, 10KB
    __shared__ __hip_bfloat16 Bh[128 * 40];   // 10KB

    int blk = blockIdx.x;
    int nt = blk & 15, mt = blk >> 4;
    int m0 = mt << 7, n0 = nt << 7;
    int tid = threadIdx.x;
    int w = tid >> 6, lane = tid & 63;
    int q = lane >> 4, c = lane & 15;
    int mhalf = w >> 1, nhalf = w & 1;

    f32x4 acc[4][4];
#pragma unroll
    for (int mi = 0; mi < 4; ++mi)
#pragma unroll
        for (int ni = 0; ni < 4; ++ni) acc[mi][ni] = (f32x4){0.f, 0.f, 0.f, 0.f};

    for (int kk = 0; kk < DIM; kk += 32) {
#pragma unroll
        for (int h = 0; h < 2; ++h) {
            int qq = tid + (h << 8);
            int mm = qq >> 2, s4 = (qq & 3) << 3;            // 8-bf16 (16B) segment
            size_t ga = (size_t)(m0 + mm) * DIM + kk + s4;
            size_t gb = (size_t)(n0 + mm) * DIM + kk + s4;
            int lo_off = mm * 40 + s4;
            *reinterpret_cast<int4*>(&Ah[lo_off]) = *reinterpret_cast<const int4*>(Xhi + ga);
            *reinterpret_cast<int4*>(&Bh[lo_off]) = *reinterpret_cast<const int4*>(Ehi + gb);
        }
        __syncthreads();
        bf16x8 ah[4], bh[4];
#pragma unroll
        for (int mi = 0; mi < 4; ++mi) {
            int ro = (mhalf * 64 + mi * 16 + c) * 40 + q * 8;
            ah[mi] = *reinterpret_cast<const bf16x8*>(&Ah[ro]);
        }
#pragma unroll
        for (int ni = 0; ni < 4; ++ni) {
            int ro = (nhalf * 64 + ni * 16 + c) * 40 + q * 8;
            bh[ni] = *reinterpret_cast<const bf16x8*>(&Bh[ro]);
        }
#pragma unroll
        for (int mi = 0; mi < 4; ++mi)
#pragma unroll
            for (int ni = 0; ni < 4; ++ni)
                acc[mi][ni] = __builtin_amdgcn_mfma_f32_16x16x32_bf16(ah[mi], bh[ni], acc[mi][ni], 0, 0, 0);
        __syncthreads();
    }

    int tb = (nt << 1) | nhalf;
#pragma unroll
    for (int mi = 0; mi < 4; ++mi) {
#pragma unroll
        for (int reg = 0; reg < 4; ++reg) {
            int m = m0 + mhalf * 64 + mi * 16 + q * 4 + reg;
            float xs = xsq[m];
            float bd = 3.4e38f; int bi = 0;
            float dv[4];
#pragma unroll
            for (int ni = 0; ni < 4; ++ni) {
                int n = n0 + nhalf * 64 + ni * 16 + c;
                float d2 = xs - 2.0f * acc[mi][ni][reg] + esq[n];
                dv[ni] = d2;
                if (d2 < bd) { bd = d2; bi = ni * 16 + c; }
            }
            for (int off = 1; off < 16; off <<= 1) {
                float od = __shfl_xor(bd, off, 16);
                int   oi = __shfl_xor(bi, off, 16);
                if (od < bd || (od == bd && oi < bi)) { bd = od; bi = oi; }
            }
            float thr = bd + MARGIN;
            unsigned long long bits = 0;
#pragma unroll
            for (int ni = 0; ni < 4; ++ni)
                if (dv[ni] <= thr) bits |= 1ULL << (ni * 16 + c);
            for (int off = 1; off < 16; off <<= 1)
                bits |= (unsigned long long)__shfl_xor((long long)bits, off, 16);
            if (c == 0) {
                lmin[(size_t)m * 32 + tb] =
                    ((unsigned long long)__float_as_uint(bd) << 32) | (unsigned)(n0 + nhalf * 64 + bi);
                lmask[(size_t)m * 32 + tb] = bits;
            }
        }
    }
}

// ---- Phase B (restructured): 32 rows/block, coalesced x staging, 8-lane
// group per row. Candidate order via LDS atomics is nondeterministic, but
// min over (d2, n) with explicit lower-n tie-break is order-independent ->
// result identical to R8 (bit-exact np chain, same candidate-superset logic).
#define CCAP 40
__global__ __launch_bounds__(256) void recheck_kernel(const float* __restrict__ x,
                                                      const float* __restrict__ cb,
                                                      const float* __restrict__ xsq,
                                                      const float* __restrict__ esq,
                                                      const unsigned long long* __restrict__ lmin,
                                                      const unsigned long long* __restrict__ lmask,
                                                      unsigned long long* __restrict__ keys) {
    __shared__ float xT[DIM * 33];     // [c][tl] stride 33: staging 2-way (free), dot broadcast
    __shared__ int clist[32][CCAP];
    __shared__ int ccnt[32];

    int tid = threadIdx.x;
    int blk = blockIdx.x;               // 1024 blocks
    int b = blk >> 6, t0 = (blk & 63) << 5;
    const float* xb = x + (size_t)b * DIM * TLEN + t0;

    if (tid < 32) ccnt[tid] = 0;
    {   // coalesced staging: 8 c-rows x 32 t per iter
        int tl = tid & 31, c8 = tid >> 5;
        for (int cc = 0; cc < 32; ++cc) {
            int c = (cc << 3) + c8;
            xT[c * 33 + tl] = xb[(size_t)c * TLEN + tl];
        }
    }
    __syncthreads();

    int g = tid >> 3, l3 = tid & 7;     // group g handles row t0+g
    int m = (b << 11) + t0 + g;

    // row min over 32 tiles (4 per lane, then width-8 shfl reduce)
    unsigned rmv4[4];
    unsigned rm = 0xffffffffu;
#pragma unroll
    for (int j = 0; j < 4; ++j) {
        rmv4[j] = (unsigned)(lmin[(size_t)m * 32 + l3 * 4 + j] >> 32);
        rm = min(rm, rmv4[j]);
    }
    for (int off = 1; off < 8; off <<= 1)
        rm = min(rm, (unsigned)__shfl_xor((int)rm, off, 8));
    float thr = __uint_as_float(rm) + MARGIN;

    // collect candidates from qualifying tiles
#pragma unroll
    for (int j = 0; j < 4; ++j) {
        if (__uint_as_float(rmv4[j]) <= thr) {
            int tb = l3 * 4 + j;
            unsigned long long msk = lmask[(size_t)m * 32 + tb];
            while (msk) {
                int bit = __ffsll((long long)msk) - 1;
                msk &= msk - 1;
                int pos = atomicAdd(&ccnt[g], 1);
                if (pos < CCAP) clist[g][pos] = tb * 64 + bit;
            }
        }
    }
    __syncthreads();

    int cnt = ccnt[g]; if (cnt > CCAP) cnt = CCAP;
    float xs = xsq[m];
    float bd = 3.4e38f; int bi = 0x7fffffff;
    for (int j = l3; j < cnt; j += 8) {
        int n = clist[g][j];
        const float* crow = cb + (size_t)n * DIM;
        float d = 0.f;
        for (int k = 0; k < DIM; k += 4) {     // ascending-k fmaf chain == np mm
            float4 cv = *reinterpret_cast<const float4*>(crow + k);
            d = fmaf(xT[(k + 0) * 33 + g], cv.x, d);
            d = fmaf(xT[(k + 1) * 33 + g], cv.y, d);
            d = fmaf(xT[(k + 2) * 33 + g], cv.z, d);
            d = fmaf(xT[(k + 3) * 33 + g], cv.w, d);
        }
        float d2 = __fadd_rn(__fadd_rn(xs, -2.0f * d), esq[n]);   // exact ref rounding
        if (d2 < bd || (d2 == bd && n < bi)) { bd = d2; bi = n; }
    }
    for (int off = 1; off < 8; off <<= 1) {
        float od = __shfl_xor(bd, off, 8);
        int   oi = __shfl_xor(bi, off, 8);
        if (od < bd || (od == bd && oi < bi)) { bd = od; bi = oi; }
    }
    if (l3 == 0)
        keys[m] = ((unsigned long long)__float_as_uint(bd) << 32) | (unsigned)(bi & 2047);
}

// ======== fallback path (R5): used only if ws_size is too small ========
__global__ __launch_bounds__(256) void init_keys_kernel(unsigned long long* __restrict__ keys) {
    keys[blockIdx.x * 256 + threadIdx.x] = ~0ULL;
}

__global__ __launch_bounds__(256, 4) void dist_kernel(const float* __restrict__ x,
                                                      const float* __restrict__ cb,
                                                      const float* __restrict__ xsq,
                                                      const float* __restrict__ esq,
                                                      unsigned long long* __restrict__ keys) {
    __shared__ float As[16][128];
    __shared__ float Bs[16][132];
    int blk = blockIdx.x;
    int nt = blk & 15, mt = blk >> 4;
    int m0 = mt << 7;
    int b = m0 >> 11, t0 = m0 & (TLEN - 1);
    int n0 = nt << 7;
    int tid = threadIdx.x;
    int tm = tid >> 4, tn = tid & 15;
    const float* xbase = x + (size_t)b * DIM * TLEN + t0;
    float acc[8][8] = {};
    for (int kk = 0; kk < DIM; kk += 16) {
#pragma unroll
        for (int h = 0; h < 2; ++h) {
            int qq = tid + (h << 8);
            int k = qq >> 5, mq = (qq & 31) << 2;
            float4 v = *reinterpret_cast<const float4*>(xbase + (size_t)(kk + k) * TLEN + mq);
            *reinterpret_cast<float4*>(&As[k][mq]) = v;
        }
#pragma unroll
        for (int h = 0; h < 2; ++h) {
            int qq = tid + (h << 8);
            int nr = qq >> 2, kc = (qq & 3) << 2;
            float4 v = *reinterpret_cast<const float4*>(cb + (size_t)(n0 + nr) * DIM + kk + kc);
            Bs[kc + 0][nr] = v.x; Bs[kc + 1][nr] = v.y;
            Bs[kc + 2][nr] = v.z; Bs[kc + 3][nr] = v.w;
        }
        __syncthreads();
#pragma unroll
        for (int k = 0; k < 16; ++k) {
            float4 a0 = *reinterpret_cast<const float4*>(&As[k][tm << 2]);
            float4 a1 = *reinterpret_cast<const float4*>(&As[k][64 + (tm << 2)]);
            float4 b0 = *reinterpret_cast<const float4*>(&Bs[k][tn << 2]);
            float4 b1 = *reinterpret_cast<const float4*>(&Bs[k][64 + (tn << 2)]);
            float am[8] = {a0.x, a0.y, a0.z, a0.w, a1.x, a1.y, a1.z, a1.w};
            float bn[8] = {b0.x, b0.y, b0.z, b0.w, b1.x, b1.y, b1.z, b1.w};
#pragma unroll
            for (int mi = 0; mi < 8; ++mi)
#pragma unroll
                for (int ni = 0; ni < 8; ++ni)
                    acc[mi][ni] = fmaf(am[mi], bn[ni], acc[mi][ni]);
        }
        __syncthreads();
    }
    int cn[8]; float es[8];
#pragma unroll
    for (int ni = 0; ni < 8; ++ni) {
        cn[ni] = n0 + ((ni < 4) ? (tn << 2) + ni : 60 + (tn << 2) + ni);
        es[ni] = esq[cn[ni]];
    }
#pragma unroll
    for (int mi = 0; mi < 8; ++mi) {
        int m = m0 + ((mi < 4) ? (tm << 2) + mi : 60 + (tm << 2) + mi);
        float xs = xsq[m];
        float bd = 3.4e38f;
        int bi = 0x7fffffff;
#pragma unroll
        for (int ni = 0; ni < 8; ++ni) {
            float d2 = __fadd_rn(__fadd_rn(xs, -2.0f * acc[mi][ni]), es[ni]);
            if (d2 < bd) { bd = d2; bi = cn[ni]; }
        }
        for (int off = 1; off < 16; off <<= 1) {
            float od = __shfl_xor(bd, off, 16);
            int oi = __shfl_xor(bi, off, 16);
            if (od < bd || (od == bd && oi < bi)) { bd = od; bi = oi; }
        }
        if (tn == 0) {
            unsigned long long key =
                ((unsigned long long)__float_as_uint(bd) << 32) | (unsigned)(bi & 2047);
            atomicMin(&keys[m], key);
        }
    }
}
// ======== end fallback ========

// ---- gather + STE output + idx + per-block loss sums
__global__ __launch_bounds__(256) void gather_kernel(const float* __restrict__ x,
                                                     const float* __restrict__ cb,
                                                     const unsigned long long* __restrict__ keys,
                                                     float* __restrict__ out,
                                                     float* __restrict__ bsum) {
    int e = blockIdx.x * 256 + threadIdx.x;
    int t = e & (TLEN - 1);
    int c = (e >> 11) & (DIM - 1);
    int b = e >> 19;
    int m = (b << 11) | t;
    unsigned idx = (unsigned)(keys[m]) & 2047u;
    float q = cb[(size_t)idx * DIM + c];
    float xv = x[e];
    float diff = __fsub_rn(q, xv);
    float o = __fadd_rn(xv, diff);
    out[e] = o;
    if (c == 0) out[(size_t)IDX_OFF + m] = (float)idx;

    float s = __fmul_rn(diff, diff);
    for (int off = 32; off > 0; off >>= 1) s += __shfl_down(s, off, 64);
    __shared__ float wsum[4];
    int lane = threadIdx.x & 63, wid = threadIdx.x >> 6;
    if (lane == 0) wsum[wid] = s;
    __syncthreads();
    if (threadIdx.x == 0)
        bsum[blockIdx.x] = ((wsum[0] + wsum[1]) + (wsum[2] + wsum[3]));
}

__global__ __launch_bounds__(1024) void finalize_kernel(const float* __restrict__ bsum,
                                                        float* __restrict__ out) {
    double s = 0.0;
    for (int i = threadIdx.x; i < 32768; i += 1024) s += (double)bsum[i];
    for (int off = 32; off > 0; off >>= 1) s += __shfl_down(s, off, 64);
    __shared__ double wsum[16];
    int lane = threadIdx.x & 63, wid = threadIdx.x >> 6;
    if (lane == 0) wsum[wid] = s;
    __syncthreads();
    if (threadIdx.x == 0) {
        double total = 0.0;
        for (int ww = 0; ww < 16; ++ww) total += wsum[ww];
        float mean = (float)(total / (double)NELEM);
        out[LOSS_OFF] = mean;
        out[LOSS_OFF + 1] = 0.25f * mean;
    }
}

extern "C" void kernel_launch(void* const* d_in, const int* in_sizes, int n_in,
                              void* d_out, int out_size, void* d_ws, size_t ws_size,
                              hipStream_t stream) {
    const float* x  = (const float*)d_in[0];
    const float* cb = (const float*)d_in[1];
    float* out = (float*)d_out;
    char* ws = (char*)d_ws;
    float* xsq = (float*)(ws + OFF_XSQ);
    float* esq = (float*)(ws + OFF_ESQ);
    unsigned long long* keys = (unsigned long long*)(ws + OFF_KEYS);
    float* bsum = (float*)(ws + OFF_BSUM);

    xsq_kernel<<<NROWS / 256, 256, 0, stream>>>(x, xsq);
    esq_kernel<<<KCODES / 256, 256, 0, stream>>>(cb, esq);

    if (ws_size >= WS_NEED) {
        __hip_bfloat16* Xhi = (__hip_bfloat16*)(ws + OFF_XHI);
        __hip_bfloat16* Ehi = (__hip_bfloat16*)(ws + OFF_EHI);
        unsigned long long* lmin  = (unsigned long long*)(ws + OFF_LMIN);
        unsigned long long* lmask = (unsigned long long*)(ws + OFF_MASK);
        split_x_kernel<<<NB * 8 * 32, 256, 0, stream>>>(x, Xhi);
        split_e_kernel<<<(KCODES * DIM) / 1024, 256, 0, stream>>>(cb, Ehi);
        mfma_dist_kernel<<<(NROWS / 128) * (KCODES / 128), 256, 0, stream>>>(
            Xhi, Ehi, xsq, esq, lmin, lmask);
        recheck_kernel<<<NROWS / 32, 256, 0, stream>>>(x, cb, xsq, esq, lmin, lmask, keys);
    } else {
        init_keys_kernel<<<NROWS / 256, 256, 0, stream>>>(keys);
        dist_kernel<<<(NROWS / 128) * (KCODES / 128), 256, 0, stream>>>(x, cb, xsq, esq, keys);
    }
    gather_kernel<<<NELEM / 256, 256, 0, stream>>>(x, cb, keys, out, bsum);
    finalize_kernel<<<1, 1024, 0, stream>>>(bsum, out);
}